// Round 1
// baseline (174.529 us; speedup 1.0000x reference)
//
#include <hip/hip_runtime.h>
#include <hip/hip_bf16.h>
#include <stdint.h>

// Problem constants: B=8, T=1024, C=768, H=12, hs=64
#define T_ 1024
#define C_ 768
#define H_ 12
#define HS 64

typedef __attribute__((ext_vector_type(8))) short bf16x8;
typedef __attribute__((ext_vector_type(4))) float f32x4;

#define GLOAD16(g, l) __builtin_amdgcn_global_load_lds( \
    (const __attribute__((address_space(1))) uint32_t*)(g), \
    (__attribute__((address_space(3))) uint32_t*)(l), 16, 0, 0)

__device__ __forceinline__ ushort f2b(float f) {
  uint32_t u = __builtin_bit_cast(uint32_t, f);
  u = (u + 0x7fffu + ((u >> 16) & 1u)) >> 16;   // RNE
  return (ushort)u;
}

// ---------------------------------------------------------------- convert
__global__ __launch_bounds__(256) void cvt_bf16(
    const float* __restrict__ x, const float* __restrict__ wt,
    ushort* __restrict__ xb, ushort* __restrict__ wb) {
  const int NX4 = 8192 * 768 / 4;
  const int NW4 = 2304 * 768 / 4;
  int i = blockIdx.x * 256 + threadIdx.x;
  int stride = gridDim.x * 256;
  for (int idx = i; idx < NX4; idx += stride) {
    float4 f = ((const float4*)x)[idx];
    ushort4 o;
    o.x = f2b(f.x); o.y = f2b(f.y); o.z = f2b(f.z); o.w = f2b(f.w);
    ((ushort4*)xb)[idx] = o;
  }
  for (int idx = i; idx < NW4; idx += stride) {
    float4 f = ((const float4*)wt)[idx];
    ushort4 o;
    o.x = f2b(f.x); o.y = f2b(f.y); o.z = f2b(f.z); o.w = f2b(f.w);
    ((ushort4*)wb)[idx] = o;
  }
}

// ---------------------------------------------------------------- qkv gemm
// C[m,n] = sum_k xb[m,k]*wb[n,k] + bias[n]; scatter to q/k/v [B,H,T,hs] bf16.
// 128x128 tile, BK=64, 4 waves (each 64x64), swizzled LDS (XOR slot^(row&7)).
__global__ __launch_bounds__(256) void qkv_gemm(
    const ushort* __restrict__ xb, const ushort* __restrict__ wb,
    const float* __restrict__ bias,
    ushort* __restrict__ qo, ushort* __restrict__ ko, ushort* __restrict__ vo) {
  __shared__ __align__(16) ushort As[128 * 64];
  __shared__ __align__(16) ushort Bs[128 * 64];
  const int tid = threadIdx.x, lane = tid & 63, w = tid >> 6;
  const int g = lane >> 4, l15 = lane & 15;
  const int m0 = blockIdx.y * 128, n0 = blockIdx.x * 128;
  const int wr = w >> 1, wc = w & 1;
  f32x4 acc[4][4] = {};

  for (int kk = 0; kk < 12; ++kk) {
    const int k0 = kk * 64;
    #pragma unroll
    for (int c = 0; c < 4; ++c) {
      int p = (w * 4 + c) * 64 + lane;   // 16B slot index (1024 per tile)
      int row = p >> 3, s = p & 7;
      int sc = (s ^ (row & 7)) * 8;      // pre-swizzled source column (elems)
      GLOAD16(xb + (size_t)(m0 + row) * 768 + k0 + sc, (char*)As + (w * 4 + c) * 1024);
      GLOAD16(wb + (size_t)(n0 + row) * 768 + k0 + sc, (char*)Bs + (w * 4 + c) * 1024);
    }
    __syncthreads();
    #pragma unroll
    for (int kd = 0; kd < 2; ++kd) {
      bf16x8 af[4], bf[4];
      #pragma unroll
      for (int mi = 0; mi < 4; ++mi) {
        int row = wr * 64 + mi * 16 + l15;
        af[mi] = *(const bf16x8*)((const char*)As + row * 128 + (((kd * 4 + g) ^ (row & 7)) << 4));
      }
      #pragma unroll
      for (int ni = 0; ni < 4; ++ni) {
        int row = wc * 64 + ni * 16 + l15;
        bf[ni] = *(const bf16x8*)((const char*)Bs + row * 128 + (((kd * 4 + g) ^ (row & 7)) << 4));
      }
      #pragma unroll
      for (int mi = 0; mi < 4; ++mi)
        #pragma unroll
        for (int ni = 0; ni < 4; ++ni)
          acc[mi][ni] = __builtin_amdgcn_mfma_f32_16x16x32_bf16(af[mi], bf[ni], acc[mi][ni], 0, 0, 0);
    }
    __syncthreads();
  }

  // epilogue: n0 is a multiple of 128; 768%128==0 so `which` is block-uniform
  const int which = n0 / 768;
  ushort* outp = (which == 0) ? qo : (which == 1) ? ko : vo;
  #pragma unroll
  for (int ni = 0; ni < 4; ++ni) {
    int n = n0 + wc * 64 + ni * 16 + l15;
    float bn = bias[n];
    int nin = n - which * 768;
    int h = nin >> 6, d = nin & 63;
    #pragma unroll
    for (int mi = 0; mi < 4; ++mi) {
      #pragma unroll
      for (int r = 0; r < 4; ++r) {
        int m = m0 + wr * 64 + mi * 16 + g * 4 + r;   // C/D: row=4*(l>>4)+r, col=l15
        float val = acc[mi][ni][r] + bn;
        outp[((size_t)((m >> 10) * H_ + h) * T_ + (m & (T_ - 1))) * HS + d] = f2b(val);
      }
    }
  }
}

// ---------------------------------------------------------------- v transpose
// v [bh][t][d] -> vT [bh][d][t]  (bf16), 64x64 tiles via swizzled LDS
__global__ __launch_bounds__(256) void transpose_v(
    const ushort* __restrict__ v, ushort* __restrict__ vT) {
  __shared__ __align__(16) ushort Ts[64 * 64];
  const int tid = threadIdx.x;
  const int bh = blockIdx.x, tt = blockIdx.y;
  const size_t base = (size_t)bh * (T_ * HS);
  #pragma unroll
  for (int c = 0; c < 2; ++c) {
    int p = c * 256 + tid;
    int row = p >> 3, s = p & 7;
    *(uint4*)((char*)Ts + row * 128 + ((s ^ (row & 7)) << 4)) =
        *(const uint4*)(v + base + (size_t)(tt * 64 + row) * HS + s * 8);
  }
  __syncthreads();
  #pragma unroll
  for (int c = 0; c < 2; ++c) {
    int p = c * 256 + tid;
    int d = p >> 3, s = p & 7, t0 = s * 8;
    ushort tmp[8];
    #pragma unroll
    for (int j = 0; j < 8; ++j) {
      int t = t0 + j;
      tmp[j] = *(const ushort*)((const char*)Ts + t * 128 + ((2 * d) ^ ((t & 7) << 4)));
    }
    uint4 pk;
    pk.x = (uint)tmp[0] | ((uint)tmp[1] << 16);
    pk.y = (uint)tmp[2] | ((uint)tmp[3] << 16);
    pk.z = (uint)tmp[4] | ((uint)tmp[5] << 16);
    pk.w = (uint)tmp[6] | ((uint)tmp[7] << 16);
    *(uint4*)(vT + base + (size_t)d * T_ + tt * 64 + t0) = pk;
  }
}

// ---------------------------------------------------------------- attention
// One block = one (bh, 64-row q-tile). 4 waves, each owns 16 q-rows.
// ReLU attention: no softmax state; causal -> only k-tiles <= q-tile.
__global__ __launch_bounds__(256) void attn_relu(
    const ushort* __restrict__ q, const ushort* __restrict__ k,
    const ushort* __restrict__ vT, float* __restrict__ out) {
  __shared__ __align__(16) ushort Qs[64 * 64];
  __shared__ __align__(16) ushort Ks[64 * 64];
  __shared__ __align__(16) ushort VTs[64 * 64];
  __shared__ __align__(16) ushort Ps[64 * 64];
  const int tid = threadIdx.x, lane = tid & 63, w = tid >> 6;
  const int g = lane >> 4, l15 = lane & 15;
  const int bh = blockIdx.x, qt = blockIdx.y;
  const int q0 = qt * 64;
  const size_t base = (size_t)bh * (T_ * HS);

  // stage Q tile (pre-swizzled source, linear LDS dest)
  #pragma unroll
  for (int c = 0; c < 2; ++c) {
    int p = (w * 2 + c) * 64 + lane;
    int row = p >> 3, s = p & 7;
    int sc = (s ^ (row & 7)) * 8;
    GLOAD16(q + base + (size_t)(q0 + row) * HS + sc, (char*)Qs + (w * 2 + c) * 1024);
  }

  f32x4 yacc[4] = {};
  const int qrow = w * 16 + l15;
  const int nkt = qt + 1;

  for (int kt = 0; kt < nkt; ++kt) {
    #pragma unroll
    for (int c = 0; c < 2; ++c) {
      int p = (w * 2 + c) * 64 + lane;
      int row = p >> 3, s = p & 7;
      int sc = (s ^ (row & 7)) * 8;
      GLOAD16(k + base + (size_t)(kt * 64 + row) * HS + sc, (char*)Ks + (w * 2 + c) * 1024);
      GLOAD16(vT + base + (size_t)row * T_ + kt * 64 + sc, (char*)VTs + (w * 2 + c) * 1024);
    }
    __syncthreads();

    // S = Q K^T  (wave's 16 rows x 64 cols)
    f32x4 sacc[4] = {};
    #pragma unroll
    for (int kd = 0; kd < 2; ++kd) {
      bf16x8 qf = *(const bf16x8*)((const char*)Qs + qrow * 128 + (((kd * 4 + g) ^ (qrow & 7)) << 4));
      #pragma unroll
      for (int nt = 0; nt < 4; ++nt) {
        int krow = nt * 16 + l15;
        bf16x8 kf = *(const bf16x8*)((const char*)Ks + krow * 128 + (((kd * 4 + g) ^ (krow & 7)) << 4));
        sacc[nt] = __builtin_amdgcn_mfma_f32_16x16x32_bf16(qf, kf, sacc[nt], 0, 0, 0);
      }
    }

    // scale + causal mask + ReLU -> P (bf16, swizzled LDS)
    #pragma unroll
    for (int nt = 0; nt < 4; ++nt) {
      int kj = kt * 64 + nt * 16 + l15;
      #pragma unroll
      for (int r = 0; r < 4; ++r) {
        int i = w * 16 + g * 4 + r;
        float sv = sacc[nt][r] * 0.125f;
        float pv = (kj <= q0 + i) ? fmaxf(sv, 0.0f) : 0.0f;
        *(ushort*)((char*)Ps + i * 128 + (((nt * 16 + l15) * 2) ^ ((i & 7) << 4))) = f2b(pv);
      }
    }

    // Y += P V  (wave reads only its own 16 P-rows -> no barrier needed)
    bf16x8 pf[2], vf[2][4];
    #pragma unroll
    for (int kj2 = 0; kj2 < 2; ++kj2) {
      pf[kj2] = *(const bf16x8*)((const char*)Ps + qrow * 128 + (((kj2 * 4 + g) ^ (qrow & 7)) << 4));
      #pragma unroll
      for (int nt = 0; nt < 4; ++nt) {
        int vrow = nt * 16 + l15;
        vf[kj2][nt] = *(const bf16x8*)((const char*)VTs + vrow * 128 + (((kj2 * 4 + g) ^ (vrow & 7)) << 4));
      }
    }
    #pragma unroll
    for (int kj2 = 0; kj2 < 2; ++kj2)
      #pragma unroll
      for (int nt = 0; nt < 4; ++nt)
        yacc[nt] = __builtin_amdgcn_mfma_f32_16x16x32_bf16(pf[kj2], vf[kj2][nt], yacc[nt], 0, 0, 0);

    __syncthreads();
  }

  // epilogue: out[b][t][h*64+d] (f32)
  const int bb = bh / H_, hh = bh % H_;
  #pragma unroll
  for (int nt = 0; nt < 4; ++nt) {
    #pragma unroll
    for (int r = 0; r < 4; ++r) {
      int t = q0 + w * 16 + g * 4 + r;
      int col = hh * HS + nt * 16 + l15;
      out[(size_t)(bb * T_ + t) * C_ + col] = yacc[nt][r];
    }
  }
}

// ---------------------------------------------------------------- launch
extern "C" void kernel_launch(void* const* d_in, const int* in_sizes, int n_in,
                              void* d_out, int out_size, void* d_ws, size_t ws_size,
                              hipStream_t stream) {
  const float* x    = (const float*)d_in[0];
  const float* W    = (const float*)d_in[1];
  const float* bias = (const float*)d_in[2];
  float* out = (float*)d_out;

  char* ws = (char*)d_ws;
  ushort* xb = (ushort*)ws;                       // 8192*768*2  = 12582912 B
  ushort* wb = (ushort*)(ws + 12582912);          // 2304*768*2  =  3538944 B
  ushort* qb = (ushort*)(ws + 16121856);          // 12582912 B
  ushort* kb = (ushort*)(ws + 28704768);          // 12582912 B
  ushort* vb = (ushort*)(ws + 41287680);          // 12582912 B
  ushort* vT = xb;  // xb is dead after qkv_gemm; reuse for v-transpose

  cvt_bf16<<<2048, 256, 0, stream>>>(x, W, xb, wb);
  qkv_gemm<<<dim3(18, 64), 256, 0, stream>>>(xb, wb, bias, qb, kb, vb);
  transpose_v<<<dim3(96, 16), 256, 0, stream>>>(vb, vT);
  attn_relu<<<dim3(96, 16), 256, 0, stream>>>(qb, kb, vT, out);
}

// Round 2
// 162.809 us; speedup vs baseline: 1.0720x; 1.0720x over previous
//
#include <hip/hip_runtime.h>
#include <hip/hip_bf16.h>
#include <stdint.h>

// Problem constants: B=8, T=1024, C=768, H=12, hs=64
#define T_ 1024
#define C_ 768
#define H_ 12
#define HS 64

typedef __attribute__((ext_vector_type(8))) short bf16x8;
typedef __attribute__((ext_vector_type(4))) float f32x4;

#define GLOAD16(g, l) __builtin_amdgcn_global_load_lds( \
    (const __attribute__((address_space(1))) uint32_t*)(g), \
    (__attribute__((address_space(3))) uint32_t*)(l), 16, 0, 0)

__device__ __forceinline__ ushort f2b(float f) {
  uint32_t u = __builtin_bit_cast(uint32_t, f);
  u = (u + 0x7fffu + ((u >> 16) & 1u)) >> 16;   // RNE
  return (ushort)u;
}

// ---------------------------------------------------------------- convert
__global__ __launch_bounds__(256) void cvt_bf16(
    const float* __restrict__ x, const float* __restrict__ wt,
    ushort* __restrict__ xb, ushort* __restrict__ wb) {
  const int NX4 = 8192 * 768 / 4;
  const int NW4 = 2304 * 768 / 4;
  int i = blockIdx.x * 256 + threadIdx.x;
  int stride = gridDim.x * 256;
  for (int idx = i; idx < NX4; idx += stride) {
    float4 f = ((const float4*)x)[idx];
    ushort4 o;
    o.x = f2b(f.x); o.y = f2b(f.y); o.z = f2b(f.z); o.w = f2b(f.w);
    ((ushort4*)xb)[idx] = o;
  }
  for (int idx = i; idx < NW4; idx += stride) {
    float4 f = ((const float4*)wt)[idx];
    ushort4 o;
    o.x = f2b(f.x); o.y = f2b(f.y); o.z = f2b(f.z); o.w = f2b(f.w);
    ((ushort4*)wb)[idx] = o;
  }
}

// ---------------------------------------------------------------- qkv gemm
// C[m,n] = sum_k xb[m,k]*wb[n,k] + bias[n].
// 128x128 tile, BK=32, 2-phase LDS double-buffer with prefetch (T3 minimum
// recipe): issue next tile's global_load_lds BEFORE current ds_read+MFMA;
// one barrier per K-step. LDS = 2 x (A 8KB + B 8KB) = 32KB -> 5 blocks/CU.
// Q/K outputs scatter to [B,H,T,hs] bf16; V output is written TRANSPOSED
// ([B,H,hs,T]) via an LDS transpose in the dead staging buffer.
__global__ __launch_bounds__(256) void qkv_gemm(
    const ushort* __restrict__ xb, const ushort* __restrict__ wb,
    const float* __restrict__ bias,
    ushort* __restrict__ qo, ushort* __restrict__ ko, ushort* __restrict__ vT) {
  __shared__ __align__(16) ushort smem[16384];  // 32KB
  const int tid = threadIdx.x, lane = tid & 63, w = tid >> 6;
  const int g = lane >> 4, l15 = lane & 15;
  const int m0 = blockIdx.y * 128, n0 = blockIdx.x * 128;
  const int wr = w >> 1, wc = w & 1;
  f32x4 acc[4][4] = {};

  // staging precompute: A tile 128x32 = 512 16B-slots, 2 per thread (same for B)
  // slot p: row = p>>2, s = p&3; pre-swizzled source col sc = (s ^ ((row>>1)&3))*8
  const ushort* srcA[2];
  const ushort* srcB[2];
  int dstoff[2];
  #pragma unroll
  for (int c = 0; c < 2; ++c) {
    int p = (c * 4 + w) * 64 + lane;
    int row = p >> 2, s = p & 3;
    int sc = (s ^ ((row >> 1) & 3)) * 8;
    srcA[c] = xb + (size_t)(m0 + row) * 768 + sc;
    srcB[c] = wb + (size_t)(n0 + row) * 768 + sc;
    dstoff[c] = (c * 4 + w) * 1024;
  }

#define STAGE_G(buf, k0) do { \
    char* bb_ = (char*)smem + (buf) * 16384; \
    _Pragma("unroll") \
    for (int c_ = 0; c_ < 2; ++c_) { \
      GLOAD16(srcA[c_] + (k0), bb_ + dstoff[c_]); \
      GLOAD16(srcB[c_] + (k0), bb_ + 8192 + dstoff[c_]); \
    } \
  } while (0)

  int cur = 0;
  STAGE_G(0, 0);
  __syncthreads();
  #pragma unroll 2
  for (int kk = 0; kk < 24; ++kk) {
    if (kk < 23) STAGE_G(cur ^ 1, (kk + 1) * 32);   // prefetch next tile
    const char* Ab = (const char*)smem + cur * 16384;
    const char* Bb = Ab + 8192;
    bf16x8 af[4], bfr[4];
    #pragma unroll
    for (int mi = 0; mi < 4; ++mi) {
      int r = wr * 64 + mi * 16 + l15;
      af[mi] = *(const bf16x8*)(Ab + r * 64 + ((g ^ ((r >> 1) & 3)) << 4));
    }
    #pragma unroll
    for (int ni = 0; ni < 4; ++ni) {
      int r = wc * 64 + ni * 16 + l15;
      bfr[ni] = *(const bf16x8*)(Bb + r * 64 + ((g ^ ((r >> 1) & 3)) << 4));
    }
    #pragma unroll
    for (int mi = 0; mi < 4; ++mi)
      #pragma unroll
      for (int ni = 0; ni < 4; ++ni)
        acc[mi][ni] = __builtin_amdgcn_mfma_f32_16x16x32_bf16(af[mi], bfr[ni], acc[mi][ni], 0, 0, 0);
    __syncthreads();   // drains prefetch vmcnt + protects buffer swap
    cur ^= 1;
  }

  const int which = n0 / 768;   // 768 % 128 == 0 -> block-uniform
  if (which < 2) {
    ushort* outp = (which == 0) ? qo : ko;
    #pragma unroll
    for (int ni = 0; ni < 4; ++ni) {
      int n = n0 + wc * 64 + ni * 16 + l15;
      float bn = bias[n];
      int nin = n - which * 768;
      int h = nin >> 6, d = nin & 63;
      #pragma unroll
      for (int mi = 0; mi < 4; ++mi) {
        #pragma unroll
        for (int r = 0; r < 4; ++r) {
          int m = m0 + wr * 64 + mi * 16 + g * 4 + r;   // C/D: row=4*(l>>4)+r, col=l15
          float val = acc[mi][ni][r] + bn;
          outp[((size_t)((m >> 10) * H_ + h) * T_ + (m & (T_ - 1))) * HS + d] = f2b(val);
        }
      }
    }
  } else {
    // V: transpose 128x128 through the (dead) staging LDS, store coalesced
    #pragma unroll
    for (int ni = 0; ni < 4; ++ni) {
      int n = n0 + wc * 64 + ni * 16 + l15;
      float bn = bias[n];
      int dl = wc * 64 + ni * 16 + l15;          // d_local 0..127
      #pragma unroll
      for (int mi = 0; mi < 4; ++mi) {
        #pragma unroll
        for (int r = 0; r < 4; ++r) {
          int tl = wr * 64 + mi * 16 + g * 4 + r;  // t_local 0..127
          *(ushort*)((char*)smem + dl * 256 + ((tl * 2) ^ ((dl & 7) << 4))) =
              f2b(acc[mi][ni][r] + bn);
        }
      }
    }
    __syncthreads();
    const int b = m0 >> 10, t0base = m0 & 1023;
    #pragma unroll
    for (int c = 0; c < 8; ++c) {
      int p = c * 256 + tid;
      int dl = p >> 4, tch = p & 15;
      uint4 val = *(const uint4*)((const char*)smem + dl * 256 + ((tch * 16) ^ ((dl & 7) << 4)));
      int nin = n0 + dl - 1536;
      int h = nin >> 6, dd = nin & 63;
      *(uint4*)(vT + (((size_t)(b * H_ + h) * HS + dd) << 10) + t0base + tch * 8) = val;
    }
  }
}

// ---------------------------------------------------------------- attention
// One block = one (bh, 64-row q-tile). 4 waves, each owns 16 q-rows.
// ReLU attention (no softmax state); causal -> k-tiles 0..qt only.
// Q in registers; K/V double-buffered LDS with 2-phase prefetch; 1 barrier/tile.
__global__ __launch_bounds__(256) void attn_relu(
    const ushort* __restrict__ q, const ushort* __restrict__ k,
    const ushort* __restrict__ vT, float* __restrict__ out) {
  __shared__ __align__(16) ushort smem[20480];  // 40KB: [K0 V0][K1 V1][P]
  const int tid = threadIdx.x, lane = tid & 63, w = tid >> 6;
  const int g = lane >> 4, l15 = lane & 15;
  const int bh = blockIdx.x, qt = 15 - blockIdx.y;   // heavy blocks first
  const int q0 = qt * 64;
  const size_t base = (size_t)bh * (T_ * HS);
  const int qrow = w * 16 + l15;

  // Q fragments straight from global (once per block)
  bf16x8 qf[2];
  #pragma unroll
  for (int kd = 0; kd < 2; ++kd)
    qf[kd] = *(const bf16x8*)(q + base + (size_t)(q0 + qrow) * HS + (kd * 4 + g) * 8);

  // staging precompute: K/V tiles 64x64 = 512 slots, 2 per thread each
  int rowS[2], scS[2], dstoff[2];
  #pragma unroll
  for (int c = 0; c < 2; ++c) {
    int p = (c * 4 + w) * 64 + lane;
    rowS[c] = p >> 3;
    scS[c] = ((p & 7) ^ (rowS[c] & 7)) * 8;
    dstoff[c] = (c * 4 + w) * 1024;
  }

#define STAGE_KV(buf, kt) do { \
    char* bb_ = (char*)smem + (buf) * 16384; \
    _Pragma("unroll") \
    for (int c_ = 0; c_ < 2; ++c_) { \
      GLOAD16(k + base + (size_t)((kt) * 64 + rowS[c_]) * HS + scS[c_], bb_ + dstoff[c_]); \
      GLOAD16(vT + base + (size_t)rowS[c_] * T_ + (kt) * 64 + scS[c_], bb_ + 8192 + dstoff[c_]); \
    } \
  } while (0)

  f32x4 yacc[4] = {};
  const int nkt = qt + 1;
  int cur = 0;
  STAGE_KV(0, 0);
  __syncthreads();
  for (int kt = 0; kt < nkt; ++kt) {
    if (kt + 1 < nkt) STAGE_KV(cur ^ 1, kt + 1);   // prefetch next K/V
    const char* Kb = (const char*)smem + cur * 16384;
    const char* Vb = Kb + 8192;
    char* Pb = (char*)smem + 32768;

    // S = Q K^T  (wave's 16 rows x 64 cols)
    f32x4 sacc[4] = {};
    #pragma unroll
    for (int kd = 0; kd < 2; ++kd) {
      #pragma unroll
      for (int nt = 0; nt < 4; ++nt) {
        int kr = nt * 16 + l15;
        bf16x8 kf = *(const bf16x8*)(Kb + kr * 128 + (((kd * 4 + g) ^ (kr & 7)) << 4));
        sacc[nt] = __builtin_amdgcn_mfma_f32_16x16x32_bf16(qf[kd], kf, sacc[nt], 0, 0, 0);
      }
    }

    // scale + causal mask + ReLU -> P (bf16, swizzled LDS, wave-local rows)
    #pragma unroll
    for (int nt = 0; nt < 4; ++nt) {
      int kj = kt * 64 + nt * 16 + l15;
      #pragma unroll
      for (int r = 0; r < 4; ++r) {
        int i = w * 16 + g * 4 + r;
        float sv = sacc[nt][r] * 0.125f;
        float pv = (kj <= q0 + i) ? fmaxf(sv, 0.0f) : 0.0f;
        *(ushort*)(Pb + i * 128 + (((nt * 16 + l15) * 2) ^ ((i & 7) << 4))) = f2b(pv);
      }
    }

    // Y += P V   (wave reads only its own 16 P-rows -> no barrier)
    bf16x8 pf[2], vf[2][4];
    #pragma unroll
    for (int kj2 = 0; kj2 < 2; ++kj2) {
      pf[kj2] = *(const bf16x8*)(Pb + qrow * 128 + (((kj2 * 4 + g) ^ (qrow & 7)) << 4));
      #pragma unroll
      for (int nt = 0; nt < 4; ++nt) {
        int vr = nt * 16 + l15;
        vf[kj2][nt] = *(const bf16x8*)(Vb + vr * 128 + (((kj2 * 4 + g) ^ (vr & 7)) << 4));
      }
    }
    #pragma unroll
    for (int kj2 = 0; kj2 < 2; ++kj2)
      #pragma unroll
      for (int nt = 0; nt < 4; ++nt)
        yacc[nt] = __builtin_amdgcn_mfma_f32_16x16x32_bf16(pf[kj2], vf[kj2][nt], yacc[nt], 0, 0, 0);

    __syncthreads();
    cur ^= 1;
  }

  // epilogue: out[b][t][h*64+d] (f32)
  const int bb = bh / H_, hh = bh % H_;
  #pragma unroll
  for (int nt = 0; nt < 4; ++nt) {
    #pragma unroll
    for (int r = 0; r < 4; ++r) {
      int t = q0 + w * 16 + g * 4 + r;
      int col = hh * HS + nt * 16 + l15;
      out[(size_t)(bb * T_ + t) * C_ + col] = yacc[nt][r];
    }
  }
}

// ---------------------------------------------------------------- launch
extern "C" void kernel_launch(void* const* d_in, const int* in_sizes, int n_in,
                              void* d_out, int out_size, void* d_ws, size_t ws_size,
                              hipStream_t stream) {
  const float* x    = (const float*)d_in[0];
  const float* W    = (const float*)d_in[1];
  const float* bias = (const float*)d_in[2];
  float* out = (float*)d_out;

  char* ws = (char*)d_ws;
  ushort* xb = (ushort*)ws;                       // 8192*768*2  = 12582912 B
  ushort* wb = (ushort*)(ws + 12582912);          // 2304*768*2  =  3538944 B
  ushort* qb = (ushort*)(ws + 16121856);          // 12582912 B
  ushort* kb = (ushort*)(ws + 28704768);          // 12582912 B
  ushort* vT = (ushort*)(ws + 41287680);          // 12582912 B  [B,H,hs,T]

  cvt_bf16<<<2048, 256, 0, stream>>>(x, W, xb, wb);
  qkv_gemm<<<dim3(18, 64), 256, 0, stream>>>(xb, wb, bias, qb, kb, vT);
  attn_relu<<<dim3(96, 16), 256, 0, stream>>>(qb, kb, vT, out);
}